// Round 1
// baseline (434.752 us; speedup 1.0000x reference)
//
#include <hip/hip_runtime.h>
#include <math.h>

#define N_NODES 100000
#define DIMS 128
#define WL_STRIDE 129  // +1 pad: compute-read bank = (o+i)%32 -> 2-way (free)

// wz[n][o] = b[o] + sum_i z[n][i] * W[o][i]
// Block = 256 threads = 4 waves. Block covers 32 rows.
// wave w: colhalf = w&1 (o = colhalf*64 + lane), rgroup = w>>1 -> 16 rows each.
// z row data is wave-uniform -> force SGPR path (s_load) via readfirstlane.
__global__ __launch_bounds__(256, 2)
void wz_kernel(const float* __restrict__ z, const float* __restrict__ W,
               const float* __restrict__ b, float* __restrict__ wz) {
    __shared__ float wlds[DIMS * WL_STRIDE];
    const int t = threadIdx.x;

    // Stage W into LDS: 16384 floats = 4096 float4, 16 per thread.
    #pragma unroll
    for (int it = 0; it < 16; ++it) {
        int flat = it * 256 + t;          // 0..4095
        int i4   = (flat & 31) * 4;       // inner dim offset
        int o    = flat >> 5;             // 0..127
        float4 v = *(const float4*)(W + o * DIMS + i4);
        wlds[o * WL_STRIDE + i4 + 0] = v.x;
        wlds[o * WL_STRIDE + i4 + 1] = v.y;
        wlds[o * WL_STRIDE + i4 + 2] = v.z;
        wlds[o * WL_STRIDE + i4 + 3] = v.w;
    }
    __syncthreads();

    const int lane = t & 63;
    const int wave = t >> 6;
    const int o = (wave & 1) * 64 + lane;
    const int rgroup = __builtin_amdgcn_readfirstlane(wave >> 1);
    const int rbase = blockIdx.x * 32 + rgroup * 16;   // N = 3125*32 exactly
    const float* __restrict__ zb = z + (size_t)rbase * DIMS;
    const float* __restrict__ wrow = wlds + o * WL_STRIDE;

    float acc[16];
    #pragma unroll
    for (int r = 0; r < 16; ++r) acc[r] = 0.0f;

    for (int i0 = 0; i0 < DIMS; i0 += 4) {
        const float w0 = wrow[i0 + 0];
        const float w1 = wrow[i0 + 1];
        const float w2 = wrow[i0 + 2];
        const float w3 = wrow[i0 + 3];
        #pragma unroll
        for (int r = 0; r < 16; ++r) {
            // wave-uniform address -> s_load_dwordx4
            float4 zv = *(const float4*)(zb + r * DIMS + i0);
            acc[r] = fmaf(zv.x, w0,
                     fmaf(zv.y, w1,
                     fmaf(zv.z, w2,
                     fmaf(zv.w, w3, acc[r]))));
        }
    }

    const float bias = b[o];
    #pragma unroll
    for (int r = 0; r < 16; ++r) {
        wz[(size_t)(rbase + r) * DIMS + o] = acc[r] + bias;  // coalesced over o
    }
}

// One edge per 32-lane group: coalesced 512 B row reads, shfl-xor reduce.
__global__ __launch_bounds__(256)
void edge_kernel(const float* __restrict__ z, const float* __restrict__ wz,
                 const int* __restrict__ src, const int* __restrict__ dst,
                 float* __restrict__ out, int E) {
    const int t = blockIdx.x * 256 + threadIdx.x;
    const int e = t >> 5;
    const int l = t & 31;
    if (e >= E) return;

    const int s = src[e];   // same addr across the 32-lane group -> broadcast
    const int d = dst[e];

    float4 a = *((const float4*)(z  + (size_t)s * DIMS) + l);
    float4 w = *((const float4*)(wz + (size_t)d * DIMS) + l);
    float p = fmaf(a.x, w.x, fmaf(a.y, w.y, fmaf(a.z, w.z, a.w * w.w)));

    // reduce across the 32-lane group (xor offsets < 32 stay in-group on wave64)
    p += __shfl_xor(p, 16);
    p += __shfl_xor(p, 8);
    p += __shfl_xor(p, 4);
    p += __shfl_xor(p, 2);
    p += __shfl_xor(p, 1);

    if (l == 0) {
        out[e] = 1.0f / (1.0f + __expf(-p));  // robust for all finite p
    }
}

extern "C" void kernel_launch(void* const* d_in, const int* in_sizes, int n_in,
                              void* d_out, int out_size, void* d_ws, size_t ws_size,
                              hipStream_t stream) {
    const float* z  = (const float*)d_in[0];
    const int*   ei = (const int*)d_in[1];   // [2, E] int32
    const float* W  = (const float*)d_in[2];
    const float* b  = (const float*)d_in[3];
    float* out = (float*)d_out;

    const int E = in_sizes[1] / 2;
    float* wz = (float*)d_ws;                 // N*D*4 = 51.2 MB scratch

    wz_kernel<<<N_NODES / 32, 256, 0, stream>>>(z, W, b, wz);

    const int total = E * 32;                 // 32 lanes per edge
    edge_kernel<<<(total + 255) / 256, 256, 0, stream>>>(z, wz, ei, ei + E, out, E);
}

// Round 2
// 349.301 us; speedup vs baseline: 1.2446x; 1.2446x over previous
//
#include <hip/hip_runtime.h>
#include <math.h>

#define N_NODES 100000
#define DIMS 128
#define SZ 132   // LDS row stride in floats: 16B-aligned, conflict-free patterns

// wz[n][o] = b[o] + sum_i z[n][i] * W[o][i]
// Block = 256 threads, tile 64 rows x 64 cols, thread tile 4x4.
// ct = t&15 -> cols cbase + ct + 16k (k=0..3)  [132*1 stride -> 2-way free]
// rt = t>>4 -> rows rbase + 4*rt + j (j=0..3)  [4-addr broadcast -> free]
__global__ __launch_bounds__(256, 2)
void wz_kernel(const float* __restrict__ z, const float* __restrict__ W,
               const float* __restrict__ b, float* __restrict__ wz) {
    __shared__ float zl[64 * SZ];
    __shared__ float wl[64 * SZ];
    const int t = threadIdx.x;
    const int bx = blockIdx.x;
    const int rbase = (bx >> 1) * 64;
    const int cbase = (bx & 1) * 64;

    // Stage both tiles: 64 rows x 128 floats each = 2048 float4; 8 per thread.
    #pragma unroll
    for (int it = 0; it < 8; ++it) {
        int f = it * 256 + t;
        int r = f >> 5;
        int i4 = (f & 31) << 2;
        int gr = rbase + r;
        if (gr >= N_NODES) gr = N_NODES - 1;   // clamp (stores are guarded)
        float4 zv = *(const float4*)(z + (size_t)gr * DIMS + i4);
        *(float4*)(zl + r * SZ + i4) = zv;     // coalesced, conflict-free b128
        float4 wv = *(const float4*)(W + (size_t)(cbase + r) * DIMS + i4);
        *(float4*)(wl + r * SZ + i4) = wv;
    }
    __syncthreads();

    const int ct = t & 15;
    const int rt = t >> 4;

    float acc[4][4];
    #pragma unroll
    for (int j = 0; j < 4; ++j)
        #pragma unroll
        for (int k = 0; k < 4; ++k) acc[j][k] = 0.0f;

    for (int i4 = 0; i4 < DIMS; i4 += 4) {
        float4 zf[4], wf[4];
        #pragma unroll
        for (int j = 0; j < 4; ++j)
            zf[j] = *(const float4*)(zl + (4 * rt + j) * SZ + i4);
        #pragma unroll
        for (int k = 0; k < 4; ++k)
            wf[k] = *(const float4*)(wl + (ct + 16 * k) * SZ + i4);
        #pragma unroll
        for (int j = 0; j < 4; ++j)
            #pragma unroll
            for (int k = 0; k < 4; ++k)
                acc[j][k] = fmaf(zf[j].x, wf[k].x,
                            fmaf(zf[j].y, wf[k].y,
                            fmaf(zf[j].z, wf[k].z,
                            fmaf(zf[j].w, wf[k].w, acc[j][k]))));
    }

    float bv[4];
    #pragma unroll
    for (int k = 0; k < 4; ++k) bv[k] = b[cbase + ct + 16 * k];

    #pragma unroll
    for (int j = 0; j < 4; ++j) {
        int gr = rbase + 4 * rt + j;
        if (gr < N_NODES) {
            float* outp = wz + (size_t)gr * DIMS + cbase;
            #pragma unroll
            for (int k = 0; k < 4; ++k)
                outp[ct + 16 * k] = acc[j][k] + bv[k];
        }
    }
}

// 4 edges per 32-lane group: 8 independent 512B row gathers in flight,
// int4 index load, float4 output store. shfl-xor reduce (<32 stays in-group).
__global__ __launch_bounds__(256)
void edge_kernel(const float* __restrict__ z, const float* __restrict__ wz,
                 const int* __restrict__ src, const int* __restrict__ dst,
                 float* __restrict__ out, int E) {
    const int t = blockIdx.x * 256 + threadIdx.x;
    const int g = t >> 5;
    const int l = t & 31;
    const int e0 = g << 2;
    if (e0 >= E) return;

    const int4 s4 = *(const int4*)(src + e0);
    const int4 d4 = *(const int4*)(dst + e0);

    float4 a0 = ((const float4*)(z  + (size_t)s4.x * DIMS))[l];
    float4 a1 = ((const float4*)(z  + (size_t)s4.y * DIMS))[l];
    float4 a2 = ((const float4*)(z  + (size_t)s4.z * DIMS))[l];
    float4 a3 = ((const float4*)(z  + (size_t)s4.w * DIMS))[l];
    float4 w0 = ((const float4*)(wz + (size_t)d4.x * DIMS))[l];
    float4 w1 = ((const float4*)(wz + (size_t)d4.y * DIMS))[l];
    float4 w2 = ((const float4*)(wz + (size_t)d4.z * DIMS))[l];
    float4 w3 = ((const float4*)(wz + (size_t)d4.w * DIMS))[l];

    float p0 = fmaf(a0.x, w0.x, fmaf(a0.y, w0.y, fmaf(a0.z, w0.z, a0.w * w0.w)));
    float p1 = fmaf(a1.x, w1.x, fmaf(a1.y, w1.y, fmaf(a1.z, w1.z, a1.w * w1.w)));
    float p2 = fmaf(a2.x, w2.x, fmaf(a2.y, w2.y, fmaf(a2.z, w2.z, a2.w * w2.w)));
    float p3 = fmaf(a3.x, w3.x, fmaf(a3.y, w3.y, fmaf(a3.z, w3.z, a3.w * w3.w)));

    #pragma unroll
    for (int o = 16; o >= 1; o >>= 1) {
        p0 += __shfl_xor(p0, o);
        p1 += __shfl_xor(p1, o);
        p2 += __shfl_xor(p2, o);
        p3 += __shfl_xor(p3, o);
    }

    if (l == 0) {
        float4 r;
        r.x = 1.0f / (1.0f + __expf(-p0));
        r.y = 1.0f / (1.0f + __expf(-p1));
        r.z = 1.0f / (1.0f + __expf(-p2));
        r.w = 1.0f / (1.0f + __expf(-p3));
        *(float4*)(out + e0) = r;
    }
}

extern "C" void kernel_launch(void* const* d_in, const int* in_sizes, int n_in,
                              void* d_out, int out_size, void* d_ws, size_t ws_size,
                              hipStream_t stream) {
    const float* z  = (const float*)d_in[0];
    const int*   ei = (const int*)d_in[1];   // [2, E] int32
    const float* W  = (const float*)d_in[2];
    const float* b  = (const float*)d_in[3];
    float* out = (float*)d_out;

    const int E = in_sizes[1] / 2;
    float* wz = (float*)d_ws;                 // N*D*4 = 51.2 MB scratch

    const int row_tiles = (N_NODES + 63) / 64;        // 1563
    wz_kernel<<<row_tiles * 2, 256, 0, stream>>>(z, W, b, wz);

    const int groups = (E + 3) / 4;                   // 400000
    const int total  = groups * 32;
    edge_kernel<<<(total + 255) / 256, 256, 0, stream>>>(z, wz, ei, ei + E, out, E);
}

// Round 4
// 269.287 us; speedup vs baseline: 1.6145x; 1.2971x over previous
//
#include <hip/hip_runtime.h>
#include <math.h>

#define N_NODES 100000
#define DIMS 128
#define SZ 132   // LDS row stride (floats): 16B-aligned, breaks pow-2 conflicts

typedef _Float16 f16_t;
typedef f16_t half4 __attribute__((ext_vector_type(4)));

// Computes wz16[n][o] = (fp16)(b[o] + sum_i z[n][i]*W[o][i]) and z16 = (fp16)z.
// Grid: ceil(N/128) blocks x 256 threads; tile 128 rows x all 128 cols.
// W staged once in LDS; z read straight from global (each row read by exactly
// one (wave,rt) group; 16 same-address lanes coalesce to one fetch).
// Thread tile 8x8: 256 FMA per 8 global + 8 LDS reads -> VALU-bound.
__global__ __launch_bounds__(256, 2)
void wz_kernel(const float* __restrict__ z, const float* __restrict__ W,
               const float* __restrict__ b,
               f16_t* __restrict__ z16, f16_t* __restrict__ wz16) {
    __shared__ float wl[DIMS * SZ];
    const int t = threadIdx.x;

    #pragma unroll
    for (int it = 0; it < 16; ++it) {      // 128x128 floats = 4096 float4
        int f  = it * 256 + t;
        int r  = f >> 5;
        int i4 = (f & 31) << 2;
        *(float4*)(wl + r * SZ + i4) = *(const float4*)(W + r * DIMS + i4);
    }
    __syncthreads();

    const int ct = t & 15;                 // col fragment: cols ct + 16k
    const int rt = t >> 4;                 // row fragment: rows rbase + j
    const int rbase = blockIdx.x * 128 + rt * 8;

    int gr[8];
    #pragma unroll
    for (int j = 0; j < 8; ++j) {
        int r = rbase + j;
        gr[j] = r < N_NODES ? r : N_NODES - 1;   // clamp loads; stores guarded
    }

    float acc[8][8];
    #pragma unroll
    for (int j = 0; j < 8; ++j)
        #pragma unroll
        for (int k = 0; k < 8; ++k) acc[j][k] = 0.0f;

    for (int i4 = 0; i4 < DIMS; i4 += 4) {
        float4 zf[8];
        #pragma unroll
        for (int j = 0; j < 8; ++j)
            zf[j] = *(const float4*)(z + (size_t)gr[j] * DIMS + i4);
        float4 wf[8];
        #pragma unroll
        for (int k = 0; k < 8; ++k)
            wf[k] = *(const float4*)(wl + (ct + 16 * k) * SZ + i4);
        #pragma unroll
        for (int j = 0; j < 8; ++j)
            #pragma unroll
            for (int k = 0; k < 8; ++k)
                acc[j][k] = fmaf(zf[j].x, wf[k].x,
                            fmaf(zf[j].y, wf[k].y,
                            fmaf(zf[j].z, wf[k].z,
                            fmaf(zf[j].w, wf[k].w, acc[j][k]))));

        // Fused z -> fp16 emission: one ct-lane per chunk stores 8B per row.
        if (ct == ((i4 >> 2) & 15)) {
            #pragma unroll
            for (int j = 0; j < 8; ++j) {
                if (rbase + j < N_NODES) {
                    half4 h = { (f16_t)zf[j].x, (f16_t)zf[j].y,
                                (f16_t)zf[j].z, (f16_t)zf[j].w };
                    *(half4*)(z16 + (size_t)(rbase + j) * DIMS + i4) = h;
                }
            }
        }
    }

    float bv[8];
    #pragma unroll
    for (int k = 0; k < 8; ++k) bv[k] = b[ct + 16 * k];

    #pragma unroll
    for (int j = 0; j < 8; ++j) {
        if (rbase + j < N_NODES) {
            f16_t* op = wz16 + (size_t)(rbase + j) * DIMS;
            #pragma unroll
            for (int k = 0; k < 8; ++k)
                op[ct + 16 * k] = (f16_t)(acc[j][k] + bv[k]);
        }
    }
}

__device__ __forceinline__ float dot4h(half4 a, half4 w) {
    return fmaf((float)a.x, (float)w.x,
           fmaf((float)a.y, (float)w.y,
           fmaf((float)a.z, (float)w.z, (float)a.w * (float)w.w)));
}

// 4 edges per 32-lane group; fp16 rows (256 B each, 8 B per lane).
__global__ __launch_bounds__(256)
void edge_kernel(const f16_t* __restrict__ z16, const f16_t* __restrict__ wz16,
                 const int* __restrict__ src, const int* __restrict__ dst,
                 float* __restrict__ out, int E) {
    const int t = blockIdx.x * 256 + threadIdx.x;
    const int g = t >> 5;
    const int l = t & 31;
    const int e0 = g << 2;
    if (e0 >= E) return;

    const int4 s4 = *(const int4*)(src + e0);
    const int4 d4 = *(const int4*)(dst + e0);

    half4 a0 = ((const half4*)(z16  + (size_t)s4.x * DIMS))[l];
    half4 a1 = ((const half4*)(z16  + (size_t)s4.y * DIMS))[l];
    half4 a2 = ((const half4*)(z16  + (size_t)s4.z * DIMS))[l];
    half4 a3 = ((const half4*)(z16  + (size_t)s4.w * DIMS))[l];
    half4 w0 = ((const half4*)(wz16 + (size_t)d4.x * DIMS))[l];
    half4 w1 = ((const half4*)(wz16 + (size_t)d4.y * DIMS))[l];
    half4 w2 = ((const half4*)(wz16 + (size_t)d4.z * DIMS))[l];
    half4 w3 = ((const half4*)(wz16 + (size_t)d4.w * DIMS))[l];

    float p0 = dot4h(a0, w0);
    float p1 = dot4h(a1, w1);
    float p2 = dot4h(a2, w2);
    float p3 = dot4h(a3, w3);

    #pragma unroll
    for (int o = 16; o >= 1; o >>= 1) {
        p0 += __shfl_xor(p0, o);
        p1 += __shfl_xor(p1, o);
        p2 += __shfl_xor(p2, o);
        p3 += __shfl_xor(p3, o);
    }

    if (l == 0) {
        float4 r;
        r.x = 1.0f / (1.0f + __expf(-p0));
        r.y = 1.0f / (1.0f + __expf(-p1));
        r.z = 1.0f / (1.0f + __expf(-p2));
        r.w = 1.0f / (1.0f + __expf(-p3));
        *(float4*)(out + e0) = r;
    }
}

extern "C" void kernel_launch(void* const* d_in, const int* in_sizes, int n_in,
                              void* d_out, int out_size, void* d_ws, size_t ws_size,
                              hipStream_t stream) {
    const float* z  = (const float*)d_in[0];
    const int*   ei = (const int*)d_in[1];   // [2, E] int32
    const float* W  = (const float*)d_in[2];
    const float* b  = (const float*)d_in[3];
    float* out = (float*)d_out;

    const int E = in_sizes[1] / 2;

    f16_t* z16  = (f16_t*)d_ws;                                   // 25.6 MB
    f16_t* wz16 = (f16_t*)((char*)d_ws + (size_t)N_NODES * DIMS * 2); // 25.6 MB

    const int row_blocks = (N_NODES + 127) / 128;   // 782
    wz_kernel<<<row_blocks, 256, 0, stream>>>(z, W, b, z16, wz16);

    const int groups = (E + 3) / 4;                 // 400000 (E % 4 == 0)
    const int total  = groups * 32;
    edge_kernel<<<(total + 255) / 256, 256, 0, stream>>>(z16, wz16, ei, ei + E, out, E);
}

// Round 5
// 218.324 us; speedup vs baseline: 1.9913x; 1.2334x over previous
//
#include <hip/hip_runtime.h>
#include <math.h>

#define N_NODES 100000
#define DIMS 128
#define RS 136   // LDS W16 row stride in halves (272 B, 16B-aligned, breaks pow-2)

typedef _Float16 f16_t;
typedef f16_t half4 __attribute__((ext_vector_type(4)));
typedef f16_t f16x8 __attribute__((ext_vector_type(8)));
typedef float f32x4 __attribute__((ext_vector_type(4)));

// wz16 = (fp16)(z @ W^T + b), z16 = (fp16)z, via mfma_f32_16x16x32_f16.
// Block = 256 = 4 waves; each wave owns a 16-row strip, block covers 64 rows.
// W (fp16) staged in LDS once; every wave reads all 8 col-tiles from it.
// A-frag: lane holds z[m=lane&15][quad*8..+7] per 32-wide k-chunk (4 chunks);
// the same registers are stored to z16 (fused convert, each element once).
// C-frag: col=lane&15, row=quad*4+reg (verified m89/m91).
__global__ __launch_bounds__(256, 4)
void wz_kernel(const float* __restrict__ z, const float* __restrict__ W,
               const float* __restrict__ b,
               f16_t* __restrict__ z16, f16_t* __restrict__ wz16) {
    __shared__ f16_t wl[DIMS * RS];
    const int t = threadIdx.x;

    // Stage W -> fp16 LDS: 128x128 = 4096 float4 chunks, 16 per thread.
    #pragma unroll
    for (int it = 0; it < 16; ++it) {
        int f  = it * 256 + t;
        int r  = f >> 5;             // W row (output col) 0..127
        int i4 = (f & 31) << 2;      // k offset 0..124
        float4 v = *(const float4*)(W + r * DIMS + i4);
        half4 h = { (f16_t)v.x, (f16_t)v.y, (f16_t)v.z, (f16_t)v.w };
        *(half4*)(wl + r * RS + i4) = h;
    }
    __syncthreads();

    const int lane = t & 63;
    const int wave = t >> 6;
    const int m    = lane & 15;
    const int quad = lane >> 4;
    const int row  = blockIdx.x * 64 + wave * 16 + m;      // A row for this lane
    const int grow = row < N_NODES ? row : N_NODES - 1;    // clamp loads

    // A fragments for the full K=128 (4 chunks of 32), fused z16 emission.
    f16x8 afrag[4];
    #pragma unroll
    for (int c = 0; c < 4; ++c) {
        const int k0 = c * 32 + quad * 8;
        float4 v0 = *(const float4*)(z + (size_t)grow * DIMS + k0);
        float4 v1 = *(const float4*)(z + (size_t)grow * DIMS + k0 + 4);
        f16x8 a = { (f16_t)v0.x, (f16_t)v0.y, (f16_t)v0.z, (f16_t)v0.w,
                    (f16_t)v1.x, (f16_t)v1.y, (f16_t)v1.z, (f16_t)v1.w };
        afrag[c] = a;
        if (row < N_NODES)
            *(f16x8*)(z16 + (size_t)row * DIMS + k0) = a;  // 16B store, exact cover
    }

    // 8 column tiles x 4 k-chunks of MFMA.
    f32x4 acc[8];
    #pragma unroll
    for (int nt = 0; nt < 8; ++nt) acc[nt] = (f32x4){0.f, 0.f, 0.f, 0.f};

    #pragma unroll
    for (int nt = 0; nt < 8; ++nt) {
        #pragma unroll
        for (int c = 0; c < 4; ++c) {
            f16x8 bfrag = *(const f16x8*)(wl + (nt * 16 + m) * RS + c * 32 + quad * 8);
            acc[nt] = __builtin_amdgcn_mfma_f32_16x16x32_f16(afrag[c], bfrag, acc[nt], 0, 0, 0);
        }
    }

    // Epilogue: bias + fp16 store. Lane covers col nt*16+m, rows quad*4+r.
    const int rbase2 = blockIdx.x * 64 + wave * 16 + quad * 4;
    #pragma unroll
    for (int nt = 0; nt < 8; ++nt) {
        const float bv = b[nt * 16 + m];
        #pragma unroll
        for (int r = 0; r < 4; ++r) {
            const int gr2 = rbase2 + r;
            if (gr2 < N_NODES)
                wz16[(size_t)gr2 * DIMS + nt * 16 + m] = (f16_t)(acc[nt][r] + bv);
        }
    }
}

__device__ __forceinline__ float dot4h(half4 a, half4 w) {
    return fmaf((float)a.x, (float)w.x,
           fmaf((float)a.y, (float)w.y,
           fmaf((float)a.z, (float)w.z, (float)a.w * (float)w.w)));
}

// 4 edges per 32-lane group; fp16 rows (256 B each, 8 B per lane).
__global__ __launch_bounds__(256)
void edge_kernel(const f16_t* __restrict__ z16, const f16_t* __restrict__ wz16,
                 const int* __restrict__ src, const int* __restrict__ dst,
                 float* __restrict__ out, int E) {
    const int t = blockIdx.x * 256 + threadIdx.x;
    const int g = t >> 5;
    const int l = t & 31;
    const int e0 = g << 2;
    if (e0 >= E) return;

    const int4 s4 = *(const int4*)(src + e0);
    const int4 d4 = *(const int4*)(dst + e0);

    half4 a0 = ((const half4*)(z16  + (size_t)s4.x * DIMS))[l];
    half4 a1 = ((const half4*)(z16  + (size_t)s4.y * DIMS))[l];
    half4 a2 = ((const half4*)(z16  + (size_t)s4.z * DIMS))[l];
    half4 a3 = ((const half4*)(z16  + (size_t)s4.w * DIMS))[l];
    half4 w0 = ((const half4*)(wz16 + (size_t)d4.x * DIMS))[l];
    half4 w1 = ((const half4*)(wz16 + (size_t)d4.y * DIMS))[l];
    half4 w2 = ((const half4*)(wz16 + (size_t)d4.z * DIMS))[l];
    half4 w3 = ((const half4*)(wz16 + (size_t)d4.w * DIMS))[l];

    float p0 = dot4h(a0, w0);
    float p1 = dot4h(a1, w1);
    float p2 = dot4h(a2, w2);
    float p3 = dot4h(a3, w3);

    #pragma unroll
    for (int o = 16; o >= 1; o >>= 1) {
        p0 += __shfl_xor(p0, o);
        p1 += __shfl_xor(p1, o);
        p2 += __shfl_xor(p2, o);
        p3 += __shfl_xor(p3, o);
    }

    if (l == 0) {
        float4 r;
        r.x = 1.0f / (1.0f + __expf(-p0));
        r.y = 1.0f / (1.0f + __expf(-p1));
        r.z = 1.0f / (1.0f + __expf(-p2));
        r.w = 1.0f / (1.0f + __expf(-p3));
        *(float4*)(out + e0) = r;
    }
}

extern "C" void kernel_launch(void* const* d_in, const int* in_sizes, int n_in,
                              void* d_out, int out_size, void* d_ws, size_t ws_size,
                              hipStream_t stream) {
    const float* z  = (const float*)d_in[0];
    const int*   ei = (const int*)d_in[1];   // [2, E] int32
    const float* W  = (const float*)d_in[2];
    const float* b  = (const float*)d_in[3];
    float* out = (float*)d_out;

    const int E = in_sizes[1] / 2;

    f16_t* z16  = (f16_t*)d_ws;                                       // 25.6 MB
    f16_t* wz16 = (f16_t*)((char*)d_ws + (size_t)N_NODES * DIMS * 2); // 25.6 MB

    const int row_blocks = (N_NODES + 63) / 64;     // 1563
    wz_kernel<<<row_blocks, 256, 0, stream>>>(z, W, b, z16, wz16);

    const int groups = (E + 3) / 4;                 // 400000 (E % 4 == 0)
    const int total  = groups * 32;
    edge_kernel<<<(total + 255) / 256, 256, 0, stream>>>(z16, wz16, ei, ei + E, out, E);
}